// Round 10
// baseline (368.185 us; speedup 1.0000x reference)
//
#include <hip/hip_runtime.h>
#include <math.h>

// Problem: y (8,3,256,256) f32, atoms (256,3,8,8) f32. ATOM=8 STRIDE=4 ->
// Hp=Wp=63, NPATCH=8*63*63=31752, D=192, K=256 atoms, 25 ISTA iterations.
// ISTA in G-form: c_{t+1} = shrink(G c_t + q/L), G = I - X/L.
#define NPATCH 31752
#define TILE   64          // patches per block = 2 streams x 32
#define PSTR   200         // p_lds row stride in f16 (400 B)

typedef _Float16 f16;
typedef __attribute__((ext_vector_type(2))) _Float16 f16x2;
typedef __attribute__((ext_vector_type(4))) _Float16 f16x4;
typedef __attribute__((ext_vector_type(8))) _Float16 f16x8;
typedef __attribute__((ext_vector_type(2))) __fp16   hf16x2;   // cvt_pkrtz return type
typedef __attribute__((ext_vector_type(4))) float    f32x4;
#define MFMA16 __builtin_amdgcn_mfma_f32_16x16x32_f16

union HU { f16x2 h; hf16x2 g; unsigned u; };

__device__ __forceinline__ f16x2 pk2(float a, float b)
{
    HU r; r.g = __builtin_amdgcn_cvt_pkrtz(a, b);
    return r.h;
}

// soft-threshold on a packed f16 pair: sign(v) * max(|v| - thr, 0)
__device__ __forceinline__ f16x2 shrink2(f16x2 v, f16x2 thr2)
{
    HU a; a.h = v;
    unsigned sgn = a.u & 0x80008000u;
    a.u &= 0x7FFF7FFFu;
    f16x2 t = a.h - thr2;
    t = __builtin_elementwise_max(t, (f16x2)(f16)0);
    HU r; r.h = t; r.u |= sgn;
    return r.h;
}

// ---------------------------------------------------------------------------
// K1: fused normalize + pack. Block b = atom row b (192 threads = 3 waves).
// Writes A (f32), As (row sums), Ap/Ab f16 fragment arrays; zeroes scal.
__global__ void fusedpack_kernel(const float* __restrict__ atoms,
                                 float* __restrict__ A, float* __restrict__ As,
                                 f16* __restrict__ Ap, f16* __restrict__ Ab,
                                 float* __restrict__ scal)
{
    __shared__ float part[6];
    const int b = blockIdx.x, t = threadIdx.x;    // 192 threads
    if (b == 0 && t < 32) scal[t] = 0.0f;         // zero traces for sq chain
    float v = atoms[b*192 + t];
    float s = v*v, r = v;
    #pragma unroll
    for (int m = 1; m < 64; m <<= 1) { s += __shfl_xor(s, m, 64); r += __shfl_xor(r, m, 64); }
    const int wv = t >> 6, lane = t & 63;
    if (lane == 0) { part[wv] = s; part[3 + wv] = r; }
    __syncthreads();
    s = part[0] + part[1] + part[2];
    r = part[3] + part[4] + part[5];
    float rn = 1.0f / sqrtf(s);
    float a  = v * rn;
    A[b*192 + t] = a;
    if (t == 0) As[b] = r * rn;
    f16 ah = (f16)a;
    // Ap: (row=b, col=t) -> e = ((I*6+ks)*64 + lane)*8 + j
    {
        int I = b >> 4, l16 = b & 15;
        int ks = t >> 5, q = (t >> 3) & 3, j = t & 7;
        Ap[(((I*6 + ks)*64) + q*16 + l16)*8 + j] = ah;
    }
    // Ab: (k=b, d=t) -> u = ((dt*8+ks)*64 + lane)*8 + j
    {
        int dt = t >> 4, dl = t & 15;
        int ks = b >> 5, q = (b >> 3) & 3, j = b & 7;
        Ab[(((dt*8 + ks)*64) + q*16 + dl)*8 + j] = ah;
    }
}

// ---------------------------------------------------------------------------
// K2: X = A A^T (256 x 256) fp32  [R1-proven multi-block form, ~2.5 us]
__global__ void x_kernel(const float* __restrict__ A, float* __restrict__ X)
{
    __shared__ float arow[192];
    int i = blockIdx.x, j = threadIdx.x;    // 256 blocks x 256 threads
    if (j < 192) arow[j] = A[i*192 + j];
    __syncthreads();
    float s = 0.0f;
    #pragma unroll 4
    for (int d = 0; d < 192; d += 4) {
        float4 av = *(const float4*)&A[j*192 + d];
        s += arow[d]*av.x + arow[d+1]*av.y + arow[d+2]*av.z + arow[d+3]*av.w;
    }
    X[i*256 + j] = s;
}

// ---------------------------------------------------------------------------
// K3 (x9): trace-normalized squaring [R1-proven multi-block form].
// Mout = (Min/r_prev)^2, r_cur = tr(Mout). After 9 squarings,
// L = prod r_u^(2^-u) = tr(X^512)^(1/512), rel err ~2e-5.
__global__ void sq_kernel(const float* __restrict__ Min, float* __restrict__ Mout,
                          float* __restrict__ scal, int tprev, int tcur)
{
    __shared__ float row[256];
    int i = blockIdx.x, j = threadIdx.x;
    float inv = tprev ? (1.0f / scal[tprev]) : 1.0f;
    row[j] = Min[i*256 + j];
    __syncthreads();
    float s = 0.0f;
    #pragma unroll 4
    for (int k = 0; k < 256; ++k) s += row[k] * Min[k*256 + j];
    float val = s * inv * inv;
    Mout[i*256 + j] = val;
    if (j == i) atomicAdd(&scal[tcur], val);
}

// K4: finalize L, 1/L, thr
__global__ void lfin_kernel(float* scal)
{
    if (threadIdx.x == 0) {
        float a = 0.0f;
        #pragma unroll
        for (int u = 1; u <= 9; ++u) a += exp2f(-(float)u) * log2f(scal[u]);
        float L = exp2f(a);
        scal[16] = 1.0f / L;
        scal[17] = 0.1f / L;       // LMBDA / L
    }
}

// ---------------------------------------------------------------------------
// K5: G = I - X/L, written as packed f16 A-operand fragments
// Gp[I=0..15][ks=0..7][lane][j].  Runs AFTER lfin (needs invL).
__global__ void gpack_kernel(const float* __restrict__ X, const float* __restrict__ scal,
                             f16* __restrict__ Gp)
{
    __shared__ float xrow[256];
    int i = blockIdx.x, j = threadIdx.x;
    const float invL = scal[16];
    xrow[j] = (i == j ? 1.0f : 0.0f) - X[i*256 + j] * invL;
    __syncthreads();
    if (j < 32) {
        int ks = j >> 2, q = j & 3;
        f16x8 h;
        #pragma unroll
        for (int u = 0; u < 8; ++u) h[u] = (f16)xrow[ks*32 + q*8 + u];
        int I = i >> 4, lane = q*16 + (i & 15);
        *(f16x8*)&Gp[(((I*8 + ks)*64) + lane)*8] = h;
    }
}

// ---------------------------------------------------------------------------
// K6: mega kernel. 256 threads / 4 waves; TILE=64 = 2 streams x 32 patches;
// fragment-linear c_lds; dual-stream pipelined ISTA; phase 3 scatter-adds
// (rf+mean)/count directly into out (divcnt folded in).
__global__ __launch_bounds__(256, 2)
void mega_kernel(const float* __restrict__ y,
                 const f16* __restrict__ Gp, const f16* __restrict__ Ap,
                 const f16* __restrict__ Ab, const float* __restrict__ As,
                 const float* __restrict__ scal, float* __restrict__ out)
{
    __shared__ f16      p_lds[TILE * PSTR];    // 25600 B
    __shared__ f16      c_lds[2 * 16 * 512];   // 32768 B: [st][ct*8+ks][lane*8+j]
    __shared__ float    mean_lds[TILE];
    __shared__ float    msum[512];
    __shared__ unsigned pco[TILE];

    const int tid  = threadIdx.x;
    const int base = blockIdx.x * TILE;
    const int wv = tid >> 6, lane = tid & 63, quad = lane >> 4, l16 = lane & 15;
    const float invL = scal[16];
    const float thr  = scal[17];
    const f16x2 thr2 = { (f16)thr, (f16)thr };

    #define CWADDR(st, rt, ct) \
        ((st)*8192 + ((ct)*8 + (wv*2 + ((rt)>>1)))*512 \
         + ((((rt)&1)*2 + (quad>>1))*16 + l16)*8 + (quad&1)*4)

    // ---- G-slice into registers (64 rows x 256 cols f16 per wave)
    f16x8 greg[4][8];
    {
        const f16x8* GpV = (const f16x8*)Gp;
        #pragma unroll
        for (int rt = 0; rt < 4; ++rt)
            #pragma unroll
            for (int ks = 0; ks < 8; ++ks)
                greg[rt][ks] = GpV[((wv*4 + rt)*8 + ks)*64 + lane];
    }

    // ---- phase 0: extraction, 2 passes (8 threads/patch, 24 f32 each)
    #pragma unroll
    for (int p = 0; p < 2; ++p) {
        int n_l = p*32 + (tid >> 3), qq = tid & 7;
        int n = base + n_l; if (n >= NPATCH) n = NPATCH - 1;
        int b = n / 3969, rem = n - b * 3969;
        int r = rem / 63, sc = rem - r * 63;
        if (qq == 0) pco[n_l] = ((unsigned)b << 16) | ((unsigned)r << 8) | (unsigned)sc;
        float s = 0.0f;
        #pragma unroll
        for (int u = 0; u < 3; ++u) {
            int d  = qq * 24 + u * 8;
            int ch = d >> 6, id = (d & 63) >> 3;
            const float* src = &y[((b*3 + ch)*256 + (r*4 + id))*256 + sc*4];
            float4 a = *(const float4*)src;
            float4 bq = *(const float4*)(src + 4);
            s += a.x + a.y + a.z + a.w + bq.x + bq.y + bq.z + bq.w;
            f16x8 h = { (f16)a.x, (f16)a.y, (f16)a.z, (f16)a.w,
                        (f16)bq.x, (f16)bq.y, (f16)bq.z, (f16)bq.w };
            *(f16x8*)&p_lds[n_l * PSTR + d] = h;
        }
        msum[p*256 + tid] = s;
    }
    __syncthreads();
    if (tid < TILE) {
        int p = tid >> 5, bse = (tid & 31) * 8;
        float s = 0.0f;
        #pragma unroll
        for (int u = 0; u < 8; ++u) s += msum[p*256 + bse + u];
        mean_lds[tid] = s * (1.0f / 192.0f);
    }
    __syncthreads();

    // ---- phase 1: q = A p^T per stream; qs packed f16; c1 = shrink(qs)
    f16x2 qslo[2][4][2], qshi[2][4][2];
    const f16x8* ApV = (const f16x8*)Ap;
    #pragma unroll
    for (int st = 0; st < 2; ++st) {
        f32x4 qf[4][2];
        #pragma unroll
        for (int rt = 0; rt < 4; ++rt)
            #pragma unroll
            for (int ct = 0; ct < 2; ++ct) qf[rt][ct] = (f32x4){0,0,0,0};
        #pragma unroll
        for (int ks = 0; ks < 6; ++ks) {
            f16x8 bf[2];
            #pragma unroll
            for (int ct = 0; ct < 2; ++ct)
                bf[ct] = *(const f16x8*)&p_lds[(st*32 + ct*16 + l16)*PSTR + ks*32 + quad*8];
            #pragma unroll
            for (int rt = 0; rt < 4; ++rt) {
                f16x8 af = ApV[((wv*4 + rt)*6 + ks)*64 + lane];
                #pragma unroll
                for (int ct = 0; ct < 2; ++ct)
                    qf[rt][ct] = MFMA16(af, bf[ct], qf[rt][ct], 0, 0, 0);
            }
        }
        #pragma unroll
        for (int rt = 0; rt < 4; ++rt) {
            float a0 = As[wv*64 + rt*16 + quad*4 + 0];
            float a1 = As[wv*64 + rt*16 + quad*4 + 1];
            float a2 = As[wv*64 + rt*16 + quad*4 + 2];
            float a3 = As[wv*64 + rt*16 + quad*4 + 3];
            #pragma unroll
            for (int ct = 0; ct < 2; ++ct) {
                float mn = mean_lds[st*32 + ct*16 + l16];
                float q0 = (qf[rt][ct][0] - mn*a0) * invL;
                float q1 = (qf[rt][ct][1] - mn*a1) * invL;
                float q2 = (qf[rt][ct][2] - mn*a2) * invL;
                float q3 = (qf[rt][ct][3] - mn*a3) * invL;
                f16x2 lo = pk2(q0, q1);
                f16x2 hi = pk2(q2, q3);
                qslo[st][rt][ct] = lo;  qshi[st][rt][ct] = hi;
                f16x2 clo = shrink2(lo, thr2);
                f16x2 chi = shrink2(hi, thr2);
                f16x4 cc; cc[0]=clo[0]; cc[1]=clo[1]; cc[2]=chi[0]; cc[3]=chi[1];
                *(f16x4*)&c_lds[CWADDR(st, rt, ct)] = cc;
            }
        }
    }
    __syncthreads();

    // ---- phase 2: 24 iterations, dual-stream pipelined
    for (int it = 0; it < 24; ++it) {
        f32x4 af[4][2];
        #pragma unroll
        for (int rt = 0; rt < 4; ++rt)
            #pragma unroll
            for (int ct = 0; ct < 2; ++ct) af[rt][ct] = (f32x4){0,0,0,0};
        #pragma unroll
        for (int ks = 0; ks < 8; ++ks) {
            f16x8 b0 = *(const f16x8*)&c_lds[(ks)*512 + lane*8];
            f16x8 b1 = *(const f16x8*)&c_lds[(8 + ks)*512 + lane*8];
            #pragma unroll
            for (int rt = 0; rt < 4; ++rt) {
                af[rt][0] = MFMA16(greg[rt][ks], b0, af[rt][0], 0, 0, 0);
                af[rt][1] = MFMA16(greg[rt][ks], b1, af[rt][1], 0, 0, 0);
            }
        }
        __syncthreads();                       // all waves done reading cA
        #pragma unroll
        for (int rt = 0; rt < 4; ++rt)
            #pragma unroll
            for (int ct = 0; ct < 2; ++ct) {
                f16x2 vlo = pk2(af[rt][ct][0], af[rt][ct][1]) + qslo[0][rt][ct];
                f16x2 vhi = pk2(af[rt][ct][2], af[rt][ct][3]) + qshi[0][rt][ct];
                vlo = shrink2(vlo, thr2);
                vhi = shrink2(vhi, thr2);
                f16x4 cc; cc[0]=vlo[0]; cc[1]=vlo[1]; cc[2]=vhi[0]; cc[3]=vhi[1];
                *(f16x4*)&c_lds[CWADDR(0, rt, ct)] = cc;
            }
        #pragma unroll
        for (int rt = 0; rt < 4; ++rt)
            #pragma unroll
            for (int ct = 0; ct < 2; ++ct) af[rt][ct] = (f32x4){0,0,0,0};
        #pragma unroll
        for (int ks = 0; ks < 8; ++ks) {
            f16x8 b0 = *(const f16x8*)&c_lds[8192 + (ks)*512 + lane*8];
            f16x8 b1 = *(const f16x8*)&c_lds[8192 + (8 + ks)*512 + lane*8];
            #pragma unroll
            for (int rt = 0; rt < 4; ++rt) {
                af[rt][0] = MFMA16(greg[rt][ks], b0, af[rt][0], 0, 0, 0);
                af[rt][1] = MFMA16(greg[rt][ks], b1, af[rt][1], 0, 0, 0);
            }
        }
        __syncthreads();                       // all waves done reading cB
        #pragma unroll
        for (int rt = 0; rt < 4; ++rt)
            #pragma unroll
            for (int ct = 0; ct < 2; ++ct) {
                f16x2 vlo = pk2(af[rt][ct][0], af[rt][ct][1]) + qslo[1][rt][ct];
                f16x2 vhi = pk2(af[rt][ct][2], af[rt][ct][3]) + qshi[1][rt][ct];
                vlo = shrink2(vlo, thr2);
                vhi = shrink2(vhi, thr2);
                f16x4 cc; cc[0]=vlo[0]; cc[1]=vlo[1]; cc[2]=vhi[0]; cc[3]=vhi[1];
                *(f16x4*)&c_lds[CWADDR(1, rt, ct)] = cc;
            }
    }
    __syncthreads();

    // ---- phase 3: rec = c^T A + mean, scaled by 1/coverage-count, scatter-
    // added into out (divcnt folded in: out = sum(contrib/count) == sum/count).
    const int nt = wv >> 1, dtb = 6 * (wv & 1);
    const f16x8* AbV = (const f16x8*)Ab;
    #pragma unroll
    for (int st = 0; st < 2; ++st) {
        f32x4 rf[6];
        #pragma unroll
        for (int u = 0; u < 6; ++u) rf[u] = (f32x4){0,0,0,0};
        #pragma unroll
        for (int ks = 0; ks < 8; ++ks) {
            f16x8 afr = *(const f16x8*)&c_lds[st*8192 + (nt*8 + ks)*512 + lane*8];
            #pragma unroll
            for (int u = 0; u < 6; ++u) {
                f16x8 bb = AbV[((dtb + u)*8 + ks)*64 + lane];
                rf[u] = MFMA16(afr, bb, rf[u], 0, 0, 0);
            }
        }
        #pragma unroll
        for (int g = 0; g < 4; ++g) {
            int nl = nt*16 + quad*4 + g;
            int n  = base + st*32 + nl;
            if (n < NPATCH) {
                unsigned pc = pco[st*32 + nl];
                int b = pc >> 16, r = (pc >> 8) & 255, sc = pc & 255;
                float mn = mean_lds[st*32 + nl];
                #pragma unroll
                for (int u = 0; u < 6; ++u) {
                    int d  = (dtb + u)*16 + l16;
                    int ch = d >> 6, dh = (d & 63) >> 3, dw = d & 7;
                    int h  = r*4 + dh, w2 = sc*4 + dw;
                    int cnth = min(62, h >> 2)  - (max(h - 4, 0) >> 2) + 1;
                    int cntw = min(62, w2 >> 2) - (max(w2 - 4, 0) >> 2) + 1;
                    float rcp = 1.0f / (float)(cnth * cntw);
                    atomicAdd(&out[((b*3 + ch)*256 + (r*4 + dh))*256 + sc*4 + dw],
                              (rf[u][g] + mn) * rcp);
                }
            }
        }
    }
    #undef CWADDR
}

// ---------------------------------------------------------------------------
extern "C" void kernel_launch(void* const* d_in, const int* in_sizes, int n_in,
                              void* d_out, int out_size, void* d_ws, size_t ws_size,
                              hipStream_t stream)
{
    const float* y     = (const float*)d_in[0];
    const float* atoms = (const float*)d_in[1];
    float* out = (float*)d_out;
    float* ws  = (float*)d_ws;

    // ws layout (float offsets); all f16 regions 16B-aligned
    float* A    = ws;                       // 49152 floats
    float* As   = ws + 49152;               // 256
    float* scal = ws + 49408;               // 32
    f16*   Ap   = (f16*)(ws + 49440);       // 49152 f16
    f16*   Ab   = (f16*)(ws + 74016);       // 49152 f16
    f16*   Gp   = (f16*)(ws + 98592);       // 65536 f16
    float* X    = ws + 131360;              // 65536 floats
    float* M0   = ws + 196896;              // 65536
    float* M1   = ws + 262432;              // 65536

    (void)hipMemsetAsync(d_out, 0, (size_t)out_size * sizeof(float), stream);

    fusedpack_kernel<<<256, 192, 0, stream>>>(atoms, A, As, Ap, Ab, scal);
    x_kernel        <<<256, 256, 0, stream>>>(A, X);

    const float* src = X;
    float* dst = M0;
    for (int t = 1; t <= 9; ++t) {
        sq_kernel<<<256, 256, 0, stream>>>(src, dst, scal, t - 1, t);
        src = dst;
        dst = (dst == M0) ? M1 : M0;
    }
    lfin_kernel <<<1, 64,    0, stream>>>(scal);
    gpack_kernel<<<256, 256, 0, stream>>>(X, scal, Gp);
    mega_kernel <<<(NPATCH + TILE - 1) / TILE, 256, 0, stream>>>
        (y, Gp, Ap, Ab, As, scal, out);
}

// Round 11
// 205.834 us; speedup vs baseline: 1.7887x; 1.7887x over previous
//
#include <hip/hip_runtime.h>
#include <math.h>

// Problem: y (8,3,256,256) f32, atoms (256,3,8,8) f32. ATOM=8 STRIDE=4 ->
// Hp=Wp=63, NPATCH=8*63*63=31752, D=192, K=256 atoms, 25 ISTA iterations.
// ISTA in G-form: c_{t+1} = shrink(G c_t + q/L), G = I - X/L.
// NOTE (R10 lesson): serial graph nodes cost ~15-20 us each on this harness
// (cross-XCD L2 maintenance between dependent dispatches) -> minimize nodes.
#define NPATCH 31752
#define TILE   64          // patches per block = 2 streams x 32
#define PSTR   200         // p_lds row stride in f16 (400 B)
#define MSTR   200         // lchain LDS row stride in f16

typedef _Float16 f16;
typedef __attribute__((ext_vector_type(2))) _Float16 f16x2;
typedef __attribute__((ext_vector_type(4))) _Float16 f16x4;
typedef __attribute__((ext_vector_type(8))) _Float16 f16x8;
typedef __attribute__((ext_vector_type(2))) __fp16   hf16x2;   // cvt_pkrtz return type
typedef __attribute__((ext_vector_type(4))) float    f32x4;
#define MFMA16 __builtin_amdgcn_mfma_f32_16x16x32_f16

union HU { f16x2 h; hf16x2 g; unsigned u; };

__device__ __forceinline__ f16x2 pk2(float a, float b)
{
    HU r; r.g = __builtin_amdgcn_cvt_pkrtz(a, b);
    return r.h;
}

// soft-threshold on a packed f16 pair: sign(v) * max(|v| - thr, 0)
__device__ __forceinline__ f16x2 shrink2(f16x2 v, f16x2 thr2)
{
    HU a; a.h = v;
    unsigned sgn = a.u & 0x80008000u;
    a.u &= 0x7FFF7FFFu;
    f16x2 t = a.h - thr2;
    t = __builtin_elementwise_max(t, (f16x2)(f16)0);
    HU r; r.h = t; r.u |= sgn;
    return r.h;
}

// ---------------------------------------------------------------------------
// K1: fused normalize + pack. Block b = atom row b (192 threads = 3 waves).
// Writes A (f32), As (row sums), Ap/Ab f16 fragment arrays.
__global__ void fusedpack_kernel(const float* __restrict__ atoms,
                                 float* __restrict__ A, float* __restrict__ As,
                                 f16* __restrict__ Ap, f16* __restrict__ Ab)
{
    __shared__ float part[6];
    const int b = blockIdx.x, t = threadIdx.x;    // 192 threads
    float v = atoms[b*192 + t];
    float s = v*v, r = v;
    #pragma unroll
    for (int m = 1; m < 64; m <<= 1) { s += __shfl_xor(s, m, 64); r += __shfl_xor(r, m, 64); }
    const int wv = t >> 6, lane = t & 63;
    if (lane == 0) { part[wv] = s; part[3 + wv] = r; }
    __syncthreads();
    s = part[0] + part[1] + part[2];
    r = part[3] + part[4] + part[5];
    float rn = 1.0f / sqrtf(s);
    float a  = v * rn;
    A[b*192 + t] = a;
    if (t == 0) As[b] = r * rn;
    f16 ah = (f16)a;
    // Ap: (row=b, col=t) -> e = ((I*6+ks)*64 + lane)*8 + j
    {
        int I = b >> 4, l16 = b & 15;
        int ks = t >> 5, q = (t >> 3) & 3, j = t & 7;
        Ap[(((I*6 + ks)*64) + q*16 + l16)*8 + j] = ah;
    }
    // Ab: (k=b, d=t) -> u = ((dt*8+ks)*64 + lane)*8 + j
    {
        int dt = t >> 4, dl = t & 15;
        int ks = b >> 5, q = (b >> 3) & 3, j = b & 7;
        Ab[(((dt*8 + ks)*64) + q*16 + dl)*8 + j] = ah;
    }
}

// ---------------------------------------------------------------------------
// K2: single-block L-chain, 512 threads (8 waves, 2/SIMD for latency hiding).
// Fully LDS-resident ping-pong (2 x 76.8 KB). M = A^T A (same nonzero
// spectrum as AA^T) then 8 trace-normalized squarings; L = prod r_u^(2^-u).
// M symmetric at every step -> C-tiles written TRANSPOSED (same matrix) so
// the register index g is address-contiguous -> packed f16x4 ds_write_b64.
// Work split: wave w owns I-tiles {3(w>>1)..+2} x J-tiles {6(w&1)..+5}.
__global__ __launch_bounds__(512, 1)
void lchain_kernel(const f16* __restrict__ Ab, float* __restrict__ scal)
{
    __shared__ f16   mls[2 * 192 * MSTR];      // 153600 B
    __shared__ float red[8];
    __shared__ float trc[16];
    const int tid = threadIdx.x, wv = tid >> 6, lane = tid & 63;
    const int quad = lane >> 4, l16 = lane & 15;
    const int g3 = (wv >> 1) * 3;              // I-tile base (3 tiles)
    const int h6 = (wv & 1) * 6;               // J-tile base (6 tiles)
    const f16x8* AbV = (const f16x8*)Ab;

    // ---- phase A: M = A^T A -> mls[0] (transposed packed write)
    f32x4 acc[3][6];
    #pragma unroll
    for (int it = 0; it < 3; ++it)
        #pragma unroll
        for (int jj = 0; jj < 6; ++jj) acc[it][jj] = (f32x4){0,0,0,0};
    for (int ks = 0; ks < 8; ++ks) {
        f16x8 bf[6];
        #pragma unroll
        for (int jj = 0; jj < 6; ++jj) bf[jj] = AbV[((h6 + jj)*8 + ks)*64 + lane];
        #pragma unroll
        for (int it = 0; it < 3; ++it) {
            f16x8 af = AbV[((g3 + it)*8 + ks)*64 + lane];
            #pragma unroll
            for (int jj = 0; jj < 6; ++jj)
                acc[it][jj] = MFMA16(af, bf[jj], acc[it][jj], 0, 0, 0);
        }
    }
    #pragma unroll
    for (int it = 0; it < 3; ++it) {
        int I = g3 + it;
        #pragma unroll
        for (int jj = 0; jj < 6; ++jj) {
            int J = h6 + jj;
            f16x2 lo = pk2(acc[it][jj][0], acc[it][jj][1]);
            f16x2 hi = pk2(acc[it][jj][2], acc[it][jj][3]);
            f16x4 cc; cc[0]=lo[0]; cc[1]=lo[1]; cc[2]=hi[0]; cc[3]=hi[1];
            *(f16x4*)&mls[(J*16 + l16)*MSTR + I*16 + quad*4] = cc;
        }
    }
    __syncthreads();

    float rprev = 1.0f;
    for (int t = 1; t <= 8; ++t) {
        const f16* src = mls + ((t & 1) ^ 1) * (192 * MSTR);
        f16*       dst = mls + (t & 1) * (192 * MSTR);
        const float inv = 1.0f / rprev;
        const float inv2 = inv * inv;

        f32x4 a2[3][6];
        #pragma unroll
        for (int it = 0; it < 3; ++it)
            #pragma unroll
            for (int jj = 0; jj < 6; ++jj) a2[it][jj] = (f32x4){0,0,0,0};
        for (int ksd = 0; ksd < 6; ++ksd) {
            f16x8 bf[6];
            #pragma unroll
            for (int jj = 0; jj < 6; ++jj)
                bf[jj] = *(const f16x8*)&src[((h6 + jj)*16 + l16)*MSTR + ksd*32 + quad*8];
            #pragma unroll
            for (int it = 0; it < 3; ++it) {
                f16x8 af = *(const f16x8*)&src[((g3 + it)*16 + l16)*MSTR + ksd*32 + quad*8];
                #pragma unroll
                for (int jj = 0; jj < 6; ++jj)
                    a2[it][jj] = MFMA16(af, bf[jj], a2[it][jj], 0, 0, 0);
            }
        }
        float dsum = 0.0f;
        #pragma unroll
        for (int it = 0; it < 3; ++it) {
            int I = g3 + it;
            #pragma unroll
            for (int jj = 0; jj < 6; ++jj) {
                int J = h6 + jj;
                float v0 = a2[it][jj][0] * inv2;
                float v1 = a2[it][jj][1] * inv2;
                float v2 = a2[it][jj][2] * inv2;
                float v3 = a2[it][jj][3] * inv2;
                f16x2 lo = pk2(v0, v1);
                f16x2 hi = pk2(v2, v3);
                f16x4 cc; cc[0]=lo[0]; cc[1]=lo[1]; cc[2]=hi[0]; cc[3]=hi[1];
                *(f16x4*)&dst[(J*16 + l16)*MSTR + I*16 + quad*4] = cc;
                if (J == I) {
                    int dg = l16 - quad*4;        // diagonal when l16 == quad*4+g
                    if (dg >= 0 && dg < 4)
                        dsum += (dg == 0 ? v0 : dg == 1 ? v1 : dg == 2 ? v2 : v3);
                }
            }
        }
        #pragma unroll
        for (int m = 1; m < 64; m <<= 1) dsum += __shfl_xor(dsum, m, 64);
        if (lane == 0) red[wv] = dsum;
        __syncthreads();
        float r = red[0] + red[1] + red[2] + red[3]
                + red[4] + red[5] + red[6] + red[7];
        if (tid == 0) trc[t] = r;
        rprev = r;
        __syncthreads();           // protect red[] before next step rewrites it
    }
    if (tid == 0) {
        float a = 0.0f;
        #pragma unroll
        for (int u = 1; u <= 8; ++u) a += exp2f(-(float)u) * log2f(trc[u]);
        float L = exp2f(a);
        scal[16] = 1.0f / L;
        scal[17] = 0.1f / L;       // LMBDA / L
    }
}

// ---------------------------------------------------------------------------
// K3: G = I - (A A^T)/L from A directly, written as packed f16 A-operand
// fragments Gp[I=0..15][ks=0..7][lane][j].  Runs AFTER lchain (needs invL).
__global__ void gpack_kernel(const float* __restrict__ A, const float* __restrict__ scal,
                             f16* __restrict__ Gp)
{
    __shared__ float arow[192];
    __shared__ float xrow[256];
    int i = blockIdx.x, j = threadIdx.x;
    const float invL = scal[16];
    if (j < 192) arow[j] = A[i*192 + j];
    __syncthreads();
    float s = 0.0f;
    #pragma unroll 4
    for (int d = 0; d < 192; d += 4) {
        float4 av = *(const float4*)&A[j*192 + d];
        s += arow[d]*av.x + arow[d+1]*av.y + arow[d+2]*av.z + arow[d+3]*av.w;
    }
    xrow[j] = (i == j ? 1.0f : 0.0f) - s * invL;
    __syncthreads();
    if (j < 32) {
        int ks = j >> 2, q = j & 3;
        f16x8 h;
        #pragma unroll
        for (int u = 0; u < 8; ++u) h[u] = (f16)xrow[ks*32 + q*8 + u];
        int I = i >> 4, lane = q*16 + (i & 15);
        *(f16x8*)&Gp[(((I*8 + ks)*64) + lane)*8] = h;
    }
}

// ---------------------------------------------------------------------------
// K4: mega kernel. 256 threads / 4 waves; TILE=64 = 2 streams x 32 patches;
// fragment-linear c_lds; dual-stream pipelined ISTA; phase 3 scatter-adds
// (rf+mean)/count directly into out (coverage divide folded in).
__global__ __launch_bounds__(256, 2)
void mega_kernel(const float* __restrict__ y,
                 const f16* __restrict__ Gp, const f16* __restrict__ Ap,
                 const f16* __restrict__ Ab, const float* __restrict__ As,
                 const float* __restrict__ scal, float* __restrict__ out)
{
    __shared__ f16      p_lds[TILE * PSTR];    // 25600 B
    __shared__ f16      c_lds[2 * 16 * 512];   // 32768 B: [st][ct*8+ks][lane*8+j]
    __shared__ float    mean_lds[TILE];
    __shared__ float    msum[512];
    __shared__ unsigned pco[TILE];

    const int tid  = threadIdx.x;
    const int base = blockIdx.x * TILE;
    const int wv = tid >> 6, lane = tid & 63, quad = lane >> 4, l16 = lane & 15;
    const float invL = scal[16];
    const float thr  = scal[17];
    const f16x2 thr2 = { (f16)thr, (f16)thr };

    #define CWADDR(st, rt, ct) \
        ((st)*8192 + ((ct)*8 + (wv*2 + ((rt)>>1)))*512 \
         + ((((rt)&1)*2 + (quad>>1))*16 + l16)*8 + (quad&1)*4)

    // ---- G-slice into registers (64 rows x 256 cols f16 per wave)
    f16x8 greg[4][8];
    {
        const f16x8* GpV = (const f16x8*)Gp;
        #pragma unroll
        for (int rt = 0; rt < 4; ++rt)
            #pragma unroll
            for (int ks = 0; ks < 8; ++ks)
                greg[rt][ks] = GpV[((wv*4 + rt)*8 + ks)*64 + lane];
    }

    // ---- phase 0: extraction, 2 passes (8 threads/patch, 24 f32 each)
    #pragma unroll
    for (int p = 0; p < 2; ++p) {
        int n_l = p*32 + (tid >> 3), qq = tid & 7;
        int n = base + n_l; if (n >= NPATCH) n = NPATCH - 1;
        int b = n / 3969, rem = n - b * 3969;
        int r = rem / 63, sc = rem - r * 63;
        if (qq == 0) pco[n_l] = ((unsigned)b << 16) | ((unsigned)r << 8) | (unsigned)sc;
        float s = 0.0f;
        #pragma unroll
        for (int u = 0; u < 3; ++u) {
            int d  = qq * 24 + u * 8;
            int ch = d >> 6, id = (d & 63) >> 3;
            const float* src = &y[((b*3 + ch)*256 + (r*4 + id))*256 + sc*4];
            float4 a = *(const float4*)src;
            float4 bq = *(const float4*)(src + 4);
            s += a.x + a.y + a.z + a.w + bq.x + bq.y + bq.z + bq.w;
            f16x8 h = { (f16)a.x, (f16)a.y, (f16)a.z, (f16)a.w,
                        (f16)bq.x, (f16)bq.y, (f16)bq.z, (f16)bq.w };
            *(f16x8*)&p_lds[n_l * PSTR + d] = h;
        }
        msum[p*256 + tid] = s;
    }
    __syncthreads();
    if (tid < TILE) {
        int p = tid >> 5, bse = (tid & 31) * 8;
        float s = 0.0f;
        #pragma unroll
        for (int u = 0; u < 8; ++u) s += msum[p*256 + bse + u];
        mean_lds[tid] = s * (1.0f / 192.0f);
    }
    __syncthreads();

    // ---- phase 1: q = A p^T per stream; qs packed f16; c1 = shrink(qs)
    f16x2 qslo[2][4][2], qshi[2][4][2];
    const f16x8* ApV = (const f16x8*)Ap;
    #pragma unroll
    for (int st = 0; st < 2; ++st) {
        f32x4 qf[4][2];
        #pragma unroll
        for (int rt = 0; rt < 4; ++rt)
            #pragma unroll
            for (int ct = 0; ct < 2; ++ct) qf[rt][ct] = (f32x4){0,0,0,0};
        #pragma unroll
        for (int ks = 0; ks < 6; ++ks) {
            f16x8 bf[2];
            #pragma unroll
            for (int ct = 0; ct < 2; ++ct)
                bf[ct] = *(const f16x8*)&p_lds[(st*32 + ct*16 + l16)*PSTR + ks*32 + quad*8];
            #pragma unroll
            for (int rt = 0; rt < 4; ++rt) {
                f16x8 af = ApV[((wv*4 + rt)*6 + ks)*64 + lane];
                #pragma unroll
                for (int ct = 0; ct < 2; ++ct)
                    qf[rt][ct] = MFMA16(af, bf[ct], qf[rt][ct], 0, 0, 0);
            }
        }
        #pragma unroll
        for (int rt = 0; rt < 4; ++rt) {
            float a0 = As[wv*64 + rt*16 + quad*4 + 0];
            float a1 = As[wv*64 + rt*16 + quad*4 + 1];
            float a2 = As[wv*64 + rt*16 + quad*4 + 2];
            float a3 = As[wv*64 + rt*16 + quad*4 + 3];
            #pragma unroll
            for (int ct = 0; ct < 2; ++ct) {
                float mn = mean_lds[st*32 + ct*16 + l16];
                float q0 = (qf[rt][ct][0] - mn*a0) * invL;
                float q1 = (qf[rt][ct][1] - mn*a1) * invL;
                float q2 = (qf[rt][ct][2] - mn*a2) * invL;
                float q3 = (qf[rt][ct][3] - mn*a3) * invL;
                f16x2 lo = pk2(q0, q1);
                f16x2 hi = pk2(q2, q3);
                qslo[st][rt][ct] = lo;  qshi[st][rt][ct] = hi;
                f16x2 clo = shrink2(lo, thr2);
                f16x2 chi = shrink2(hi, thr2);
                f16x4 cc; cc[0]=clo[0]; cc[1]=clo[1]; cc[2]=chi[0]; cc[3]=chi[1];
                *(f16x4*)&c_lds[CWADDR(st, rt, ct)] = cc;
            }
        }
    }
    __syncthreads();

    // ---- phase 2: 24 iterations, dual-stream pipelined
    for (int it = 0; it < 24; ++it) {
        f32x4 af[4][2];
        #pragma unroll
        for (int rt = 0; rt < 4; ++rt)
            #pragma unroll
            for (int ct = 0; ct < 2; ++ct) af[rt][ct] = (f32x4){0,0,0,0};
        #pragma unroll
        for (int ks = 0; ks < 8; ++ks) {
            f16x8 b0 = *(const f16x8*)&c_lds[(ks)*512 + lane*8];
            f16x8 b1 = *(const f16x8*)&c_lds[(8 + ks)*512 + lane*8];
            #pragma unroll
            for (int rt = 0; rt < 4; ++rt) {
                af[rt][0] = MFMA16(greg[rt][ks], b0, af[rt][0], 0, 0, 0);
                af[rt][1] = MFMA16(greg[rt][ks], b1, af[rt][1], 0, 0, 0);
            }
        }
        __syncthreads();                       // all waves done reading cA
        #pragma unroll
        for (int rt = 0; rt < 4; ++rt)
            #pragma unroll
            for (int ct = 0; ct < 2; ++ct) {
                f16x2 vlo = pk2(af[rt][ct][0], af[rt][ct][1]) + qslo[0][rt][ct];
                f16x2 vhi = pk2(af[rt][ct][2], af[rt][ct][3]) + qshi[0][rt][ct];
                vlo = shrink2(vlo, thr2);
                vhi = shrink2(vhi, thr2);
                f16x4 cc; cc[0]=vlo[0]; cc[1]=vlo[1]; cc[2]=vhi[0]; cc[3]=vhi[1];
                *(f16x4*)&c_lds[CWADDR(0, rt, ct)] = cc;
            }
        #pragma unroll
        for (int rt = 0; rt < 4; ++rt)
            #pragma unroll
            for (int ct = 0; ct < 2; ++ct) af[rt][ct] = (f32x4){0,0,0,0};
        #pragma unroll
        for (int ks = 0; ks < 8; ++ks) {
            f16x8 b0 = *(const f16x8*)&c_lds[8192 + (ks)*512 + lane*8];
            f16x8 b1 = *(const f16x8*)&c_lds[8192 + (8 + ks)*512 + lane*8];
            #pragma unroll
            for (int rt = 0; rt < 4; ++rt) {
                af[rt][0] = MFMA16(greg[rt][ks], b0, af[rt][0], 0, 0, 0);
                af[rt][1] = MFMA16(greg[rt][ks], b1, af[rt][1], 0, 0, 0);
            }
        }
        __syncthreads();                       // all waves done reading cB
        #pragma unroll
        for (int rt = 0; rt < 4; ++rt)
            #pragma unroll
            for (int ct = 0; ct < 2; ++ct) {
                f16x2 vlo = pk2(af[rt][ct][0], af[rt][ct][1]) + qslo[1][rt][ct];
                f16x2 vhi = pk2(af[rt][ct][2], af[rt][ct][3]) + qshi[1][rt][ct];
                vlo = shrink2(vlo, thr2);
                vhi = shrink2(vhi, thr2);
                f16x4 cc; cc[0]=vlo[0]; cc[1]=vlo[1]; cc[2]=vhi[0]; cc[3]=vhi[1];
                *(f16x4*)&c_lds[CWADDR(1, rt, ct)] = cc;
            }
    }
    __syncthreads();

    // ---- phase 3: rec = c^T A + mean, scaled by 1/coverage-count, scatter-
    // added into out (out = sum(contrib/count) == sum/count).
    const int nt = wv >> 1, dtb = 6 * (wv & 1);
    const f16x8* AbV = (const f16x8*)Ab;
    #pragma unroll
    for (int st = 0; st < 2; ++st) {
        f32x4 rf[6];
        #pragma unroll
        for (int u = 0; u < 6; ++u) rf[u] = (f32x4){0,0,0,0};
        #pragma unroll
        for (int ks = 0; ks < 8; ++ks) {
            f16x8 afr = *(const f16x8*)&c_lds[st*8192 + (nt*8 + ks)*512 + lane*8];
            #pragma unroll
            for (int u = 0; u < 6; ++u) {
                f16x8 bb = AbV[((dtb + u)*8 + ks)*64 + lane];
                rf[u] = MFMA16(afr, bb, rf[u], 0, 0, 0);
            }
        }
        #pragma unroll
        for (int g = 0; g < 4; ++g) {
            int nl = nt*16 + quad*4 + g;
            int n  = base + st*32 + nl;
            if (n < NPATCH) {
                unsigned pc = pco[st*32 + nl];
                int b = pc >> 16, r = (pc >> 8) & 255, sc = pc & 255;
                float mn = mean_lds[st*32 + nl];
                #pragma unroll
                for (int u = 0; u < 6; ++u) {
                    int d  = (dtb + u)*16 + l16;
                    int ch = d >> 6, dh = (d & 63) >> 3, dw = d & 7;
                    int h  = r*4 + dh, w2 = sc*4 + dw;
                    int cnth = min(62, h >> 2)  - (max(h - 4, 0) >> 2) + 1;
                    int cntw = min(62, w2 >> 2) - (max(w2 - 4, 0) >> 2) + 1;
                    float rcp = 1.0f / (float)(cnth * cntw);
                    atomicAdd(&out[((b*3 + ch)*256 + (r*4 + dh))*256 + sc*4 + dw],
                              (rf[u][g] + mn) * rcp);
                }
            }
        }
    }
    #undef CWADDR
}

// ---------------------------------------------------------------------------
extern "C" void kernel_launch(void* const* d_in, const int* in_sizes, int n_in,
                              void* d_out, int out_size, void* d_ws, size_t ws_size,
                              hipStream_t stream)
{
    const float* y     = (const float*)d_in[0];
    const float* atoms = (const float*)d_in[1];
    float* out = (float*)d_out;
    float* ws  = (float*)d_ws;

    // ws layout (float offsets); all f16 regions 16B-aligned
    float* A    = ws;                       // 49152 floats
    float* As   = ws + 49152;               // 256
    float* scal = ws + 49408;               // 32
    f16*   Ap   = (f16*)(ws + 49440);       // 49152 f16
    f16*   Ab   = (f16*)(ws + 74016);       // 49152 f16
    f16*   Gp   = (f16*)(ws + 98592);       // 65536 f16

    (void)hipMemsetAsync(d_out, 0, (size_t)out_size * sizeof(float), stream);

    fusedpack_kernel<<<256, 192, 0, stream>>>(atoms, A, As, Ap, Ab);
    lchain_kernel   <<<1, 512,   0, stream>>>(Ab, scal);
    gpack_kernel    <<<256, 256, 0, stream>>>(A, scal, Gp);
    mega_kernel     <<<(NPATCH + TILE - 1) / TILE, 256, 0, stream>>>
        (y, Gp, Ap, Ab, As, scal, out);
}